// Round 6
// baseline (244.996 us; speedup 1.0000x reference)
//
#include <hip/hip_runtime.h>

// ---------------------------------------------------------------------------
// WindowAttention (trainingTag==2 fast path, tag==1 supported symmetrically):
//   q* = qsrc * scale; attn = softmax(q* k^T + bias); out_s = attn @ v_s
// B_=2048, N=64, H=6, hd=32, dim=192, C3=576.
//
// R6: pure-streaming reads. 1 persistent block/CU (grid 256, 1024 thr,
// ~158 KB LDS), loop 8 b-slabs. q-source buffer read as ONE linear 147-KB
// stream (addr = 4*chunk); other buffer as 1536-B k|v spans. Loads held in
// regs; slab k+1 issued before compute(k) so the only stall is the BW drain.
// V transposed during LDS write. Compute bodies = R2/R5 verified.
// ---------------------------------------------------------------------------

typedef float  f32x4  __attribute__((ext_vector_type(4)));
typedef short  bf16x8 __attribute__((ext_vector_type(8)));   // 8 bf16 (4 VGPRs)
typedef unsigned short u16x8 __attribute__((ext_vector_type(8)));
typedef unsigned short u16x4 __attribute__((ext_vector_type(4)));

__device__ __forceinline__ unsigned short f2bf(float f) {
  unsigned int u = __builtin_bit_cast(unsigned int, f);
  unsigned int r = (u + 0x7FFFu + ((u >> 16) & 1u)) >> 16;   // RNE
  return (unsigned short)r;
}

// ---------------- kernel 1: bias MLP -> fragment-ordered workspace ----------
// ws layout: bias_ws[((h*16 + tile)*64 + lane)*4 + reg], tile = mt*4 + nt,
// value = bias[h][n][m], n = nt*16 + (lane&15), m = mt*16 + (lane>>4)*4 + reg.
__global__ void bias_mlp_kernel(const float* __restrict__ W1,
                                const float* __restrict__ b1,
                                const float* __restrict__ W2,
                                const float* __restrict__ b2,
                                float* __restrict__ bias_ws) {
  int idx  = blockIdx.x * 256 + threadIdx.x;   // 24576 threads total
  int reg  = idx & 3;
  int lane = (idx >> 2) & 63;
  int tile = (idx >> 8) & 15;
  int h    = idx >> 12;
  int mt = tile >> 2, nt = tile & 3;
  int n = nt * 16 + (lane & 15);
  int m = mt * 16 + (lane >> 4) * 4 + reg;
  float dr = (float)((n >> 3) - (m >> 3));
  float dc = (float)((n & 7) - (m & 7));
  float fr = copysignf(log1pf(fabsf(dr)), dr);
  float fc = copysignf(log1pf(fabsf(dc)), dc);
  float acc = b2[h];
  for (int jj = 0; jj < 256; ++jj) {
    float hid = fmaf(fr, W1[jj], fmaf(fc, W1[256 + jj], b1[jj]));
    hid = fmaxf(hid, 0.0f);
    acc = fmaf(hid, W2[jj * 6 + h], acc);
  }
  bias_ws[idx] = acc;
}

// ---------------- kernel 2: persistent streaming dual-stream attention ------
__global__ __launch_bounds__(1024, 1)
void wattn_kernel(const float* __restrict__ qkv,
                  const float* __restrict__ mfif,
                  const float* __restrict__ bias_ws,
                  const int*   __restrict__ tagp,
                  float* __restrict__ out) {
  const int tid  = threadIdx.x;
  const int lane = tid & 63;
  const int wv   = tid >> 6;       // 0..15
  const int j    = lane & 15;
  const int g    = lane >> 4;
  const int nt   = wv & 3;         // n-tile (16 rows)
  const int s    = (wv >> 2) & 1;  // stream
  const int hh   = wv >> 3;        // head half: heads 3hh..3hh+2

  // qnat/kA/kB pitch 200 (400 B = 100 banks == 4 mod 32: 2-way max on b128)
  // vT pitch 66 (132 B = 33 banks == 1 mod 32: conflict-free by-d reads)
  __shared__ unsigned short qnat[64][200];     // q-source cols 0..192 (scaled)
  __shared__ unsigned short kA[64][200];       // stream-0 K  (all heads)
  __shared__ unsigned short kB[64][200];       // stream-1 KM (all heads)
  __shared__ unsigned short vT[2][192][66];    // [stream][d(all heads)][m]
  __shared__ unsigned short P_s[16][16][66];   // per-wave private
  __shared__ float sums[16][16];

  const int tag = *tagp;
  const float* fullp = (tag == 2) ? mfif : qkv;   // carries q-source
  const float* partp = (tag == 2) ? qkv : mfif;
  unsigned short (*kFull)[200] = (tag == 2) ? kB : kA;
  unsigned short (*kPart)[200] = (tag == 2) ? kA : kB;
  const int vFull = (tag == 2) ? 1 : 0;
  const int vPart = vFull ^ 1;
  const float scale = 0.17677669529663687f;       // 32^-0.5

  f32x4 Lf[9], Lp[6];   // in-flight slab (held across compute of prev slab)

  auto ISSUE = [&](int bb) {
    const float* fb = fullp + (size_t)bb * 36864;
    const float* pb = partp + (size_t)bb * 36864;
#pragma unroll
    for (int it = 0; it < 9; ++it)                 // perfectly linear stream
      Lf[it] = *(const f32x4*)(fb + 4 * (tid + 1024 * it));
#pragma unroll
    for (int it = 0; it < 6; ++it) {               // 1536-B k|v spans
      const int c = tid + 1024 * it;
      Lp[it] = *(const f32x4*)(pb + (size_t)(c / 96) * 576 + 192 + (c % 96) * 4);
    }
  };

  const int b0 = blockIdx.x * 8;
  ISSUE(b0);

#pragma unroll 1
  for (int k = 0; k < 8; ++k) {
    const int b = b0 + k;

    __syncthreads();   // compute of slab k-1 done reading LDS
    // ---- WRITE phase: convert + scatter to LDS (vmcnt waits land here) ----
#pragma unroll
    for (int it = 0; it < 9; ++it) {
      const int c   = tid + 1024 * it;
      const int row = c / 144;
      const int cf  = (c % 144) * 4;
      f32x4 v = Lf[it];
      if (cf < 192) {            // q-region (scaled)
        u16x4 o;
#pragma unroll
        for (int e = 0; e < 4; ++e) o[e] = f2bf(v[e] * scale);
        *(u16x4*)&qnat[row][cf] = o;
      } else if (cf < 384) {     // k-region
        u16x4 o;
#pragma unroll
        for (int e = 0; e < 4; ++e) o[e] = f2bf(v[e]);
        *(u16x4*)&kFull[row][cf - 192] = o;
      } else {                   // v-region -> transposed
        const int d0 = cf - 384;
#pragma unroll
        for (int e = 0; e < 4; ++e) vT[vFull][d0 + e][row] = f2bf(v[e]);
      }
    }
#pragma unroll
    for (int it = 0; it < 6; ++it) {
      const int c   = tid + 1024 * it;
      const int row = c / 96;
      const int cf  = 192 + (c % 96) * 4;
      f32x4 v = Lp[it];
      if (cf < 384) {
        u16x4 o;
#pragma unroll
        for (int e = 0; e < 4; ++e) o[e] = f2bf(v[e]);
        *(u16x4*)&kPart[row][cf - 192] = o;
      } else {
        const int d0 = cf - 384;
#pragma unroll
        for (int e = 0; e < 4; ++e) vT[vPart][d0 + e][row] = f2bf(v[e]);
      }
    }
    __syncthreads();   // slab k staged

    if (k < 7) ISSUE(b + 1);   // next slab streams in under compute + drain

    // ---- COMPUTE: wave = (nt, s, hh); 3 heads serial ----
    unsigned short (*Ks)[200] = s ? kB : kA;
#pragma unroll 1
    for (int h2 = 0; h2 < 3; ++h2) {
      const int h = 3 * hh + h2;

      bf16x8 bq = *(const bf16x8*)&qnat[16 * nt + j][h * 32 + g * 8];
      f32x4 bias4[4];
#pragma unroll
      for (int mt = 0; mt < 4; ++mt)
        bias4[mt] = *(const f32x4*)&bias_ws[(((h * 16) + mt * 4 + nt) * 64 + lane) * 4];

      // S^T tiles: D[m_local][n_local] = sum_d K[m][d] q*[n][d] + bias
      f32x4 acc[4];
#pragma unroll
      for (int mt = 0; mt < 4; ++mt) {
        bf16x8 ak = *(const bf16x8*)&Ks[mt * 16 + j][h * 32 + g * 8];
        acc[mt] = __builtin_amdgcn_mfma_f32_16x16x32_bf16(ak, bq, bias4[mt], 0, 0, 0);
      }

      // softmax (no max-sub, verified): unnormalized P, sums off-chain
      float t0 = 0.f, t1 = 0.f, t2 = 0.f, t3 = 0.f;
#pragma unroll
      for (int mt = 0; mt < 4; ++mt) {
        float e0 = __expf(acc[mt][0]);
        float e1 = __expf(acc[mt][1]);
        float e2 = __expf(acc[mt][2]);
        float e3 = __expf(acc[mt][3]);
        u16x4 pw;
        pw[0] = f2bf(e0); pw[1] = f2bf(e1); pw[2] = f2bf(e2); pw[3] = f2bf(e3);
        *(u16x4*)&P_s[wv][j][mt * 16 + g * 4] = pw;
        t0 += e0; t1 += e1; t2 += e2; t3 += e3;
      }
      float sum = (t0 + t1) + (t2 + t3);
      sum += __shfl_xor(sum, 16);
      sum += __shfl_xor(sum, 32);
      if (g == 0) sums[wv][j] = sum;

      // PV: x[n][d] = sum_m P[n][m] v[m][d]
      f32x4 xo[2] = {{0.f, 0.f, 0.f, 0.f}, {0.f, 0.f, 0.f, 0.f}};
#pragma unroll
      for (int kt = 0; kt < 2; ++kt) {
        bf16x8 ap = *(const bf16x8*)&P_s[wv][j][kt * 32 + g * 8];
#pragma unroll
        for (int dt = 0; dt < 2; ++dt) {
          bf16x8 bv = *(const bf16x8*)&vT[s][h * 32 + dt * 16 + j][kt * 32 + g * 8];
          xo[dt] = __builtin_amdgcn_mfma_f32_16x16x32_bf16(ap, bv, xo[dt], 0, 0, 0);
        }
      }

      // normalized store: out[b][n][h*32+d]; stream-1 offset = 2048*64*192
      f32x4 sm = *(const f32x4*)&sums[wv][4 * g];
      float inv[4];
#pragma unroll
      for (int r = 0; r < 4; ++r) inv[r] = __builtin_amdgcn_rcpf(sm[r]);
      float* ob = out + (size_t)s * 25165824 + (size_t)b * 12288 + h * 32;
#pragma unroll
      for (int dt = 0; dt < 2; ++dt)
#pragma unroll
        for (int r = 0; r < 4; ++r)
          ob[(16 * nt + g * 4 + r) * 192 + dt * 16 + j] = xo[dt][r] * inv[r];
    }
  }
}

extern "C" void kernel_launch(void* const* d_in, const int* in_sizes, int n_in,
                              void* d_out, int out_size, void* d_ws, size_t ws_size,
                              hipStream_t stream) {
  const float* qkv  = (const float*)d_in[0];
  const float* mfif = (const float*)d_in[1];
  const float* W1   = (const float*)d_in[2];
  const float* b1   = (const float*)d_in[3];
  const float* W2   = (const float*)d_in[4];
  const float* b2   = (const float*)d_in[5];
  const int*   tag  = (const int*)d_in[6];
  float* out     = (float*)d_out;
  float* bias_ws = (float*)d_ws;   // 24576 floats = 96 KiB

  hipLaunchKernelGGL(bias_mlp_kernel, dim3(96), dim3(256), 0, stream,
                     W1, b1, W2, b2, bias_ws);
  hipLaunchKernelGGL(wattn_kernel, dim3(256), dim3(1024), 0, stream,
                     qkv, mfif, bias_ws, tag, out);
}

// Round 7
// 156.589 us; speedup vs baseline: 1.5646x; 1.5646x over previous
//
#include <hip/hip_runtime.h>

// ---------------------------------------------------------------------------
// WindowAttention (trainingTag==2 fast path, tag==1 also supported):
//   q* = qsrc*scale;  attn_s = softmax(q* K_s^T + bias);  out_s = attn_s V_s
// B_=2048, N=64, H=6, hd=32, dim=192, C3=576.
//
// R7: R2 verified structure (26KB LDS, 6 blocks/CU) +
//  (a) ALL global loads issued up-front into named regs, pinned with
//      sched_barrier(0) -> ~26 vmem instrs in flight per wave (vs ~8 when
//      the compiler minimized VGPR to 40). Attacks latency-bound BW:
//      BW/CU = inflight/latency.
//  (b) R4-verified softmax: no max-subtraction, unnormalized P, deferred
//      normalization folded into the store via rcp.
// ---------------------------------------------------------------------------

typedef float  f32x4  __attribute__((ext_vector_type(4)));
typedef short  bf16x8 __attribute__((ext_vector_type(8)));   // 8 bf16 (4 VGPRs)
typedef unsigned short u16x8 __attribute__((ext_vector_type(8)));
typedef unsigned short u16x4 __attribute__((ext_vector_type(4)));

__device__ __forceinline__ unsigned short f2bf(float f) {
  unsigned int u = __builtin_bit_cast(unsigned int, f);
  unsigned int r = (u + 0x7FFFu + ((u >> 16) & 1u)) >> 16;   // RNE
  return (unsigned short)r;
}

// ---------------- kernel 1: bias MLP -> fragment-ordered workspace ----------
// ws layout: bias_ws[((h*16 + tile)*64 + lane)*4 + reg], tile = mt*4 + nt,
// value = bias[h][n][m], n = nt*16 + (lane&15), m = mt*16 + (lane>>4)*4 + reg.
__global__ void bias_mlp_kernel(const float* __restrict__ W1,
                                const float* __restrict__ b1,
                                const float* __restrict__ W2,
                                const float* __restrict__ b2,
                                float* __restrict__ bias_ws) {
  int idx  = blockIdx.x * 256 + threadIdx.x;   // 24576 threads total
  int reg  = idx & 3;
  int lane = (idx >> 2) & 63;
  int tile = (idx >> 8) & 15;
  int h    = idx >> 12;
  int mt = tile >> 2, nt = tile & 3;
  int n = nt * 16 + (lane & 15);
  int m = mt * 16 + (lane >> 4) * 4 + reg;
  float dr = (float)((n >> 3) - (m >> 3));
  float dc = (float)((n & 7) - (m & 7));
  float fr = copysignf(log1pf(fabsf(dr)), dr);
  float fc = copysignf(log1pf(fabsf(dc)), dc);
  float acc = b2[h];
  for (int jj = 0; jj < 256; ++jj) {
    float hid = fmaf(fr, W1[jj], fmaf(fc, W1[256 + jj], b1[jj]));
    hid = fmaxf(hid, 0.0f);
    acc = fmaf(hid, W2[jj * 6 + h], acc);
  }
  bias_ws[idx] = acc;
}

// ---------------- kernel 2: fused dual-stream window attention --------------
__global__ __launch_bounds__(256, 6)
void wattn_kernel(const float* __restrict__ qkv,
                  const float* __restrict__ mfif,
                  const float* __restrict__ bias_ws,
                  const int*   __restrict__ tagp,
                  float* __restrict__ out) {
  const int bid  = blockIdx.x;
  const int h    = bid % 6;
  const int b    = bid / 6;
  const int tid  = threadIdx.x;
  const int lane = tid & 63;
  const int w    = tid >> 6;        // wave id = n-tile (nt)
  const int j    = lane & 15;
  const int g    = lane >> 4;

  // pitch 36 (72B = 18 banks) and 66 (132B = 33 banks == 1 mod 32):
  // conflict-free for all b64/b128 access patterns below.
  __shared__ unsigned short k_s [64][36];
  __shared__ unsigned short km_s[64][36];
  __shared__ unsigned short vT_s[2][32][66];   // [stream][d][m]
  __shared__ unsigned short P_s [64][66];      // wave-private row slices
  __shared__ __align__(16) float sums_s[2][64];

  const int tag = *tagp;
  const float* qsrc = (tag == 2) ? mfif : qkv;   // tag2: qm; tag1: q
  const size_t base = (size_t)b * 36864;
  const float scale = 0.17677669529663687f;      // 32^-0.5

  // ================= PHASE 0: issue ALL global loads up-front ==============
  const int n_k = tid >> 2, seg = tid & 3;           // k/km staging rows
  const int d_v = tid & 31, m0_v = (tid >> 5) * 8;   // v/vm gather

  const float* pq = qsrc + base + (size_t)(16 * w + j) * 576 + h * 32 + g * 8;
  f32x4 qA = *(const f32x4*)pq;
  f32x4 qB = *(const f32x4*)(pq + 4);

  const float* pk = qkv + base + (size_t)n_k * 576 + 192 + h * 32 + seg * 8;
  f32x4 kA = *(const f32x4*)pk;
  f32x4 kB = *(const f32x4*)(pk + 4);

  const float* pm = mfif + base + (size_t)n_k * 576 + 192 + h * 32 + seg * 8;
  f32x4 mA = *(const f32x4*)pm;
  f32x4 mB = *(const f32x4*)(pm + 4);

  const float* pv  = qkv  + base + 384 + h * 32 + d_v;
  const float* pvm = mfif + base + 384 + h * 32 + d_v;
  float vv[8], vmv[8];
#pragma unroll
  for (int e = 0; e < 8; ++e) vv[e]  = pv [(size_t)(m0_v + e) * 576];
#pragma unroll
  for (int e = 0; e < 8; ++e) vmv[e] = pvm[(size_t)(m0_v + e) * 576];

  f32x4 bias4[4];
#pragma unroll
  for (int mt = 0; mt < 4; ++mt)
    bias4[mt] = *(const f32x4*)&bias_ws[(((h * 16) + mt * 4 + w) * 64 + lane) * 4];

  // pin: nothing from below may be hoisted above; no load may sink below.
  __builtin_amdgcn_sched_barrier(0);

  // ================= PHASE 1: convert + stage ==============================
  bf16x8 bq;
  {
    u16x8 oq;
#pragma unroll
    for (int e = 0; e < 4; ++e) {
      oq[e]     = f2bf(qA[e] * scale);
      oq[e + 4] = f2bf(qB[e] * scale);
    }
    bq = __builtin_bit_cast(bf16x8, oq);
  }
  {
    u16x8 ok, om;
#pragma unroll
    for (int e = 0; e < 4; ++e) {
      ok[e] = f2bf(kA[e]);  ok[e + 4] = f2bf(kB[e]);
      om[e] = f2bf(mA[e]);  om[e + 4] = f2bf(mB[e]);
    }
    *(u16x8*)&k_s [n_k][seg * 8] = ok;
    *(u16x8*)&km_s[n_k][seg * 8] = om;
  }
  {
    u16x8 ov, om;
#pragma unroll
    for (int e = 0; e < 8; ++e) { ov[e] = f2bf(vv[e]); om[e] = f2bf(vmv[e]); }
    *(u16x8*)&vT_s[0][d_v][m0_v] = ov;
    *(u16x8*)&vT_s[1][d_v][m0_v] = om;
  }
  __syncthreads();

  // ================= PHASE 2: compute (R2 body, R4 softmax) ================
#pragma unroll
  for (int s = 0; s < 2; ++s) {
    const unsigned short (*Ks)[36] = (s == 0) ? k_s : km_s;

    // S^T tiles: D[m_local][n_local] = sum_d K[m][d] * q[n][d] + bias
    f32x4 acc[4];
#pragma unroll
    for (int mt = 0; mt < 4; ++mt) {
      bf16x8 ak = *(const bf16x8*)&Ks[mt * 16 + j][g * 8];
      acc[mt] = __builtin_amdgcn_mfma_f32_16x16x32_bf16(ak, bq, bias4[mt], 0, 0, 0);
    }

    // softmax (no max-sub, verified R4-R6): unnormalized P, sums off-chain
    float t0 = 0.f, t1 = 0.f, t2 = 0.f, t3 = 0.f;
#pragma unroll
    for (int mt = 0; mt < 4; ++mt) {
      float e0 = __expf(acc[mt][0]);
      float e1 = __expf(acc[mt][1]);
      float e2 = __expf(acc[mt][2]);
      float e3 = __expf(acc[mt][3]);
      u16x4 pw;
      pw[0] = f2bf(e0); pw[1] = f2bf(e1); pw[2] = f2bf(e2); pw[3] = f2bf(e3);
      *(u16x4*)&P_s[16 * w + j][mt * 16 + g * 4] = pw;
      t0 += e0; t1 += e1; t2 += e2; t3 += e3;
    }
    float sum = (t0 + t1) + (t2 + t3);
    sum += __shfl_xor(sum, 16);
    sum += __shfl_xor(sum, 32);
    if (g == 0) sums_s[s][16 * w + j] = sum;

    // PV: x[n][d] = sum_m P[n][m] v[m][d]
    f32x4 xo[2] = {{0.f, 0.f, 0.f, 0.f}, {0.f, 0.f, 0.f, 0.f}};
#pragma unroll
    for (int kt = 0; kt < 2; ++kt) {
      bf16x8 ap = *(const bf16x8*)&P_s[16 * w + j][kt * 32 + g * 8];
#pragma unroll
      for (int dt = 0; dt < 2; ++dt) {
        bf16x8 bv = *(const bf16x8*)&vT_s[s][16 * dt + j][kt * 32 + g * 8];
        xo[dt] = __builtin_amdgcn_mfma_f32_16x16x32_bf16(ap, bv, xo[dt], 0, 0, 0);
      }
    }

    // normalized store: out[b][n][h*32+d]; stream-1 offset = 2048*64*192
    f32x4 sm = *(const f32x4*)&sums_s[s][16 * w + 4 * g];
    float inv[4];
#pragma unroll
    for (int r = 0; r < 4; ++r) inv[r] = __builtin_amdgcn_rcpf(sm[r]);
    float* ob = out + (size_t)s * 25165824 + (size_t)b * 12288 + h * 32;
#pragma unroll
    for (int dt = 0; dt < 2; ++dt)
#pragma unroll
      for (int r = 0; r < 4; ++r)
        ob[(16 * w + g * 4 + r) * 192 + dt * 16 + j] = xo[dt][r] * inv[r];
  }
}

extern "C" void kernel_launch(void* const* d_in, const int* in_sizes, int n_in,
                              void* d_out, int out_size, void* d_ws, size_t ws_size,
                              hipStream_t stream) {
  const float* qkv  = (const float*)d_in[0];
  const float* mfif = (const float*)d_in[1];
  const float* W1   = (const float*)d_in[2];
  const float* b1   = (const float*)d_in[3];
  const float* W2   = (const float*)d_in[4];
  const float* b2   = (const float*)d_in[5];
  const int*   tag  = (const int*)d_in[6];
  float* out     = (float*)d_out;
  float* bias_ws = (float*)d_ws;   // 24576 floats = 96 KiB

  hipLaunchKernelGGL(bias_mlp_kernel, dim3(96), dim3(256), 0, stream,
                     W1, b1, W2, b2, bias_ws);
  hipLaunchKernelGGL(wattn_kernel, dim3(12288), dim3(256), 0, stream,
                     qkv, mfif, bias_ws, tag, out);
}

// Round 8
// 152.782 us; speedup vs baseline: 1.6036x; 1.0249x over previous
//
#include <hip/hip_runtime.h>

// ---------------------------------------------------------------------------
// WindowAttention (trainingTag==2 fast path, tag==1 also supported):
//   q* = qsrc*scale;  attn_s = softmax(q* K_s^T + bias);  out_s = attn_s V_s
// B_=2048, N=64, H=6, hd=32, dim=192, C3=576.
//
// R8: TRUE deep-in-flight staging via __builtin_amdgcn_global_load_lds.
// k/km/v/vm staged as raw fp32 direct to LDS (8 async instrs/thread, no
// destination VGPRs -> the register allocator cannot serialize them; one
// vmcnt(0) at the barrier drains all). LDS linear (HW requirement); bank
// spread achieved by pre-swizzling the GLOBAL source address (16B-slot XOR
// with row&7) and applying the same XOR on LDS reads. V consumed directly
// from natural [m][d] via swizzled scalar reads. Compute = R7-verified.
// ---------------------------------------------------------------------------

typedef float  f32x4  __attribute__((ext_vector_type(4)));
typedef short  bf16x8 __attribute__((ext_vector_type(8)));   // 8 bf16 (4 VGPRs)
typedef unsigned short u16x8 __attribute__((ext_vector_type(8)));
typedef unsigned short u16x4 __attribute__((ext_vector_type(4)));

__device__ __forceinline__ unsigned short f2bf(float f) {
  unsigned int u = __builtin_bit_cast(unsigned int, f);
  unsigned int r = (u + 0x7FFFu + ((u >> 16) & 1u)) >> 16;   // RNE
  return (unsigned short)r;
}

#define GLD16(gp, lp)                                                         \
  __builtin_amdgcn_global_load_lds(                                           \
      (const __attribute__((address_space(1))) unsigned int*)(gp),            \
      (__attribute__((address_space(3))) unsigned int*)(lp), 16, 0, 0)

// ---------------- kernel 1: bias MLP -> fragment-ordered workspace ----------
// ws layout: bias_ws[((h*16 + tile)*64 + lane)*4 + reg], tile = mt*4 + nt,
// value = bias[h][n][m], n = nt*16 + (lane&15), m = mt*16 + (lane>>4)*4 + reg.
__global__ void bias_mlp_kernel(const float* __restrict__ W1,
                                const float* __restrict__ b1,
                                const float* __restrict__ W2,
                                const float* __restrict__ b2,
                                float* __restrict__ bias_ws) {
  int idx  = blockIdx.x * 256 + threadIdx.x;   // 24576 threads total
  int reg  = idx & 3;
  int lane = (idx >> 2) & 63;
  int tile = (idx >> 8) & 15;
  int h    = idx >> 12;
  int mt = tile >> 2, nt = tile & 3;
  int n = nt * 16 + (lane & 15);
  int m = mt * 16 + (lane >> 4) * 4 + reg;
  float dr = (float)((n >> 3) - (m >> 3));
  float dc = (float)((n & 7) - (m & 7));
  float fr = copysignf(log1pf(fabsf(dr)), dr);
  float fc = copysignf(log1pf(fabsf(dc)), dc);
  float acc = b2[h];
  for (int jj = 0; jj < 256; ++jj) {
    float hid = fmaf(fr, W1[jj], fmaf(fc, W1[256 + jj], b1[jj]));
    hid = fmaxf(hid, 0.0f);
    acc = fmaf(hid, W2[jj * 6 + h], acc);
  }
  bias_ws[idx] = acc;
}

// ---------------- kernel 2: fused dual-stream window attention --------------
__global__ __launch_bounds__(256, 3)
void wattn_kernel(const float* __restrict__ qkv,
                  const float* __restrict__ mfif,
                  const float* __restrict__ bias_ws,
                  const int*   __restrict__ tagp,
                  float* __restrict__ out) {
  const int bid  = blockIdx.x;
  const int h    = bid % 6;
  const int b    = bid / 6;
  const int tid  = threadIdx.x;
  const int lane = tid & 63;
  const int w    = tid >> 6;        // wave id = n-tile (nt)
  const int j    = lane & 15;
  const int g    = lane >> 4;

  // raw fp32 staging buffers, LDS-linear (global_load_lds requirement).
  // logical [row][col]; 16B slot sl within a row holds global slot sl^(row&7).
  __shared__ float k_f [64][32];
  __shared__ float km_f[64][32];
  __shared__ float v_f [64][32];
  __shared__ float vm_f[64][32];
  __shared__ unsigned short P_s[64][66];   // wave-private rows, pitch 66
  __shared__ __align__(16) float sums_s[2][64];

  const int tag = *tagp;
  const float* qsrc = (tag == 2) ? mfif : qkv;   // tag2: qm; tag1: q
  const size_t base = (size_t)b * 36864;
  const float scale = 0.17677669529663687f;      // 32^-0.5

  // ================= async staging: 8 global_load_lds, zero VGPRs ==========
  {
    const int ldsb = ((tid >> 6) * 64) * 16;     // wave-uniform byte base
#pragma unroll
    for (int it = 0; it < 2; ++it) {
      const int c   = it * 256 + tid;
      const int row = c >> 3;
      const int sl  = c & 7;
      const size_t gof = base + (size_t)row * 576 + ((sl ^ (row & 7)) * 4) + h * 32;
      const int lb = it * 4096 + ldsb;
      GLD16(qkv  + gof + 192, (char*)&k_f [0][0] + lb);
      GLD16(mfif + gof + 192, (char*)&km_f[0][0] + lb);
      GLD16(qkv  + gof + 384, (char*)&v_f [0][0] + lb);
      GLD16(mfif + gof + 384, (char*)&vm_f[0][0] + lb);
    }
  }

  // ---- q B-fragment + bias via registers (small, overlaps async) ----
  bf16x8 bq;
  {
    const float* pq = qsrc + base + (size_t)(16 * w + j) * 576 + h * 32 + g * 8;
    f32x4 qA = *(const f32x4*)pq;
    f32x4 qB = *(const f32x4*)(pq + 4);
    u16x8 oq;
#pragma unroll
    for (int e = 0; e < 4; ++e) {
      oq[e]     = f2bf(qA[e] * scale);
      oq[e + 4] = f2bf(qB[e] * scale);
    }
    bq = __builtin_bit_cast(bf16x8, oq);
  }
  f32x4 bias4[4];
#pragma unroll
  for (int mt = 0; mt < 4; ++mt)
    bias4[mt] = *(const f32x4*)&bias_ws[(((h * 16) + mt * 4 + w) * 64 + lane) * 4];

  __syncthreads();   // compiler emits vmcnt(0) here -> drains all async loads

  // ================= compute (R7-verified bodies) ==========================
#pragma unroll
  for (int s = 0; s < 2; ++s) {
    const float (*Kf)[32] = s ? km_f : k_f;
    const float (*Vf)[32] = s ? vm_f : v_f;

    // S^T tiles: A-fragment from swizzled fp32 LDS, convert, mfma
    f32x4 acc[4];
#pragma unroll
    for (int mt = 0; mt < 4; ++mt) {
      const int row = mt * 16 + j;
      const int x   = j & 7;
      f32x4 a0 = *(const f32x4*)&Kf[row][((2 * g) ^ x) * 4];
      f32x4 a1 = *(const f32x4*)&Kf[row][((2 * g + 1) ^ x) * 4];
      u16x8 ok;
#pragma unroll
      for (int e = 0; e < 4; ++e) { ok[e] = f2bf(a0[e]); ok[e + 4] = f2bf(a1[e]); }
      acc[mt] = __builtin_amdgcn_mfma_f32_16x16x32_bf16(
          __builtin_bit_cast(bf16x8, ok), bq, bias4[mt], 0, 0, 0);
    }

    // softmax (no max-sub, verified R4-R7): unnormalized P, sums off-chain
    float t0 = 0.f, t1 = 0.f, t2 = 0.f, t3 = 0.f;
#pragma unroll
    for (int mt = 0; mt < 4; ++mt) {
      float e0 = __expf(acc[mt][0]);
      float e1 = __expf(acc[mt][1]);
      float e2 = __expf(acc[mt][2]);
      float e3 = __expf(acc[mt][3]);
      u16x4 pw;
      pw[0] = f2bf(e0); pw[1] = f2bf(e1); pw[2] = f2bf(e2); pw[3] = f2bf(e3);
      *(u16x4*)&P_s[16 * w + j][mt * 16 + g * 4] = pw;
      t0 += e0; t1 += e1; t2 += e2; t3 += e3;
    }
    float sum = (t0 + t1) + (t2 + t3);
    sum += __shfl_xor(sum, 16);
    sum += __shfl_xor(sum, 32);
    if (g == 0) sums_s[s][16 * w + j] = sum;

    // PV: B-fragment gathered from natural [m][d] fp32 LDS (swizzled cols)
    f32x4 xo[2] = {{0.f, 0.f, 0.f, 0.f}, {0.f, 0.f, 0.f, 0.f}};
#pragma unroll
    for (int kt = 0; kt < 2; ++kt) {
      bf16x8 ap = *(const bf16x8*)&P_s[16 * w + j][kt * 32 + g * 8];
#pragma unroll
      for (int dt = 0; dt < 2; ++dt) {
        const int col = dt * 16 + j;
        const int cq  = col >> 2, cr = col & 3;
        u16x8 ov;
#pragma unroll
        for (int e = 0; e < 8; ++e) {
          const int row = kt * 32 + g * 8 + e;   // row & 7 == e
          ov[e] = f2bf(Vf[row][((cq ^ e) * 4) + cr]);
        }
        xo[dt] = __builtin_amdgcn_mfma_f32_16x16x32_bf16(
            ap, __builtin_bit_cast(bf16x8, ov), xo[dt], 0, 0, 0);
      }
    }

    // normalized store: out[b][n][h*32+d]; stream-1 offset = 2048*64*192
    f32x4 sm = *(const f32x4*)&sums_s[s][16 * w + 4 * g];
    float inv[4];
#pragma unroll
    for (int r = 0; r < 4; ++r) inv[r] = __builtin_amdgcn_rcpf(sm[r]);
    float* ob = out + (size_t)s * 25165824 + (size_t)b * 12288 + h * 32;
#pragma unroll
    for (int dt = 0; dt < 2; ++dt)
#pragma unroll
      for (int r = 0; r < 4; ++r)
        ob[(16 * w + g * 4 + r) * 192 + dt * 16 + j] = xo[dt][r] * inv[r];
  }
}

extern "C" void kernel_launch(void* const* d_in, const int* in_sizes, int n_in,
                              void* d_out, int out_size, void* d_ws, size_t ws_size,
                              hipStream_t stream) {
  const float* qkv  = (const float*)d_in[0];
  const float* mfif = (const float*)d_in[1];
  const float* W1   = (const float*)d_in[2];
  const float* b1   = (const float*)d_in[3];
  const float* W2   = (const float*)d_in[4];
  const float* b2   = (const float*)d_in[5];
  const int*   tag  = (const int*)d_in[6];
  float* out     = (float*)d_out;
  float* bias_ws = (float*)d_ws;   // 24576 floats = 96 KiB

  hipLaunchKernelGGL(bias_mlp_kernel, dim3(96), dim3(256), 0, stream,
                     W1, b1, W2, b2, bias_ws);
  hipLaunchKernelGGL(wattn_kernel, dim3(12288), dim3(256), 0, stream,
                     qkv, mfif, bias_ws, tag, out);
}